// Round 1
// baseline (436.200 us; speedup 1.0000x reference)
//
#include <hip/hip_runtime.h>

// CostVolume: out[b,c,h,x,d] = (x>=d) ? left[b,c,h,x] - right[b,c,h,x-d] : 0
// B=4, C=32, H=128, W=240, D=24 (fp32 in/out).
// Memory-write-bound: 377.5 MB output. Strategy: 6 threads per pixel, each
// thread computes 4 consecutive d values and writes one float4 -> perfectly
// coalesced 16B/lane stores. Right-image reads are row-local (960 B rows),
// L1-resident.

constexpr int D_LEVELS = 24;
constexpr int W_IMG = 240;

__global__ __launch_bounds__(256) void cost_volume_kernel(
    const float* __restrict__ left,
    const float* __restrict__ right,
    float4* __restrict__ out,
    int n_pix)  // B*C*H*W
{
    int g = blockIdx.x * blockDim.x + threadIdx.x;
    if (g >= n_pix * 6) return;

    int x_lin = g / 6;            // flat pixel index into [B,C,H,W]
    int j     = g - x_lin * 6;    // which group of 4 disparities: d = 4*j + k
    int x     = x_lin % W_IMG;    // column within the row
    int row_base = x_lin - x;     // flat index of column 0 of this row

    float lv   = left[x_lin];
    int   idx0 = x - 4 * j;       // source column for k=0 (d = 4*j)

    // d = 4*j + k  ->  src col = idx0 - k, valid iff idx0 - k >= 0.
    // Clamp load index to >= 0 (stays inside the buffer; matches jnp.clip),
    // then mask to exact 0 where invalid.
    float4 o;
    {
        int i = idx0 - 0;
        float r = right[row_base + (i > 0 ? i : 0)];
        o.x = (i >= 0) ? (lv - r) : 0.0f;
    }
    {
        int i = idx0 - 1;
        float r = right[row_base + (i > 0 ? i : 0)];
        o.y = (i >= 0) ? (lv - r) : 0.0f;
    }
    {
        int i = idx0 - 2;
        float r = right[row_base + (i > 0 ? i : 0)];
        o.z = (i >= 0) ? (lv - r) : 0.0f;
    }
    {
        int i = idx0 - 3;
        float r = right[row_base + (i > 0 ? i : 0)];
        o.w = (i >= 0) ? (lv - r) : 0.0f;
    }

    out[g] = o;  // 16 B aligned, consecutive lanes -> consecutive 16 B chunks
}

extern "C" void kernel_launch(void* const* d_in, const int* in_sizes, int n_in,
                              void* d_out, int out_size, void* d_ws, size_t ws_size,
                              hipStream_t stream) {
    const float* left  = (const float*)d_in[0];
    const float* right = (const float*)d_in[1];
    float*       out   = (float*)d_out;

    int n_pix = in_sizes[0];                 // B*C*H*W = 3,932,160
    long long total = (long long)n_pix * 6;  // one thread per float4 of output
    int  threads = 256;
    int  blocks  = (int)((total + threads - 1) / threads);

    cost_volume_kernel<<<blocks, threads, 0, stream>>>(left, right,
                                                       (float4*)out, n_pix);
}

// Round 2
// 389.025 us; speedup vs baseline: 1.1213x; 1.1213x over previous
//
#include <hip/hip_runtime.h>

// CostVolume: out[b,c,h,x,d] = (x>=d) ? left[b,c,h,x] - right[b,c,h,x-d] : 0
// B=4, C=32, H=128, W=240, D=24 (fp32 in/out). Write-bound: 377.5 MB out.
//
// R1 change: one block per (b,c,h) row. Stage the 240-float left/right rows
// into LDS with coalesced float4 loads; serve the shifted (gather) reads from
// LDS instead of L1. Stores stay 16 B/lane fully coalesced (thread q writes
// float4 q of the row, q = pix*6 + j, d = 4j+k innermost).

constexpr int W_IMG = 240;
constexpr int D_LEV = 24;
constexpr int Q_PER_ROW = W_IMG * D_LEV / 4;  // 1440 float4 per row

__global__ __launch_bounds__(256) void cost_volume_kernel(
    const float* __restrict__ left,
    const float* __restrict__ right,
    float4* __restrict__ out)
{
    __shared__ float lrow[W_IMG];
    __shared__ float rrow[W_IMG];

    const int row  = blockIdx.x;        // 0 .. B*C*H-1 (16384 rows)
    const int base = row * W_IMG;       // flat float index of column 0
    const int t    = threadIdx.x;

    // Stage: 60 float4 each for left and right (rows are 960 B, 16B-aligned).
    if (t < 60) {
        ((float4*)lrow)[t] = ((const float4*)(left + base))[t];
    } else if (t < 120) {
        ((float4*)rrow)[t - 60] = ((const float4*)(right + base))[t - 60];
    }
    __syncthreads();

    float4* __restrict__ out_row = out + (long long)row * Q_PER_ROW;

    // 1440 float4 per row, 256 threads -> 6 strided iterations (last partial).
    #pragma unroll
    for (int it = 0; it < 6; ++it) {
        int q = t + it * 256;
        if (q < Q_PER_ROW) {
            int pix = q / 6;            // magic-mul, cheap
            int j   = q - pix * 6;      // float4 group: d = 4j + k
            int i0  = pix - 4 * j;      // src col for k=0
            float lv = lrow[pix];
            float4 o;
            {
                int i = i0 - 0;
                float r = rrow[i > 0 ? i : 0];
                o.x = (i >= 0) ? (lv - r) : 0.0f;
            }
            {
                int i = i0 - 1;
                float r = rrow[i > 0 ? i : 0];
                o.y = (i >= 0) ? (lv - r) : 0.0f;
            }
            {
                int i = i0 - 2;
                float r = rrow[i > 0 ? i : 0];
                o.z = (i >= 0) ? (lv - r) : 0.0f;
            }
            {
                int i = i0 - 3;
                float r = rrow[i > 0 ? i : 0];
                o.w = (i >= 0) ? (lv - r) : 0.0f;
            }
            out_row[q] = o;             // 1 KB/wave contiguous
        }
    }
}

extern "C" void kernel_launch(void* const* d_in, const int* in_sizes, int n_in,
                              void* d_out, int out_size, void* d_ws, size_t ws_size,
                              hipStream_t stream) {
    const float* left  = (const float*)d_in[0];
    const float* right = (const float*)d_in[1];
    float*       out   = (float*)d_out;

    int n_pix = in_sizes[0];            // B*C*H*W
    int rows  = n_pix / W_IMG;          // B*C*H = 16384

    cost_volume_kernel<<<rows, 256, 0, stream>>>(left, right, (float4*)out);
}